// Round 15
// baseline (168.325 us; speedup 1.0000x reference)
//
#include <hip/hip_runtime.h>
#include <stdint.h>

#define INF    4096
#define OUTF   11008
#define NTOK   256
#define QZ_COLS (OUTF / 8)   // 1376
#define NTILES  (INF / 128)  // 32 K-tiles, one quant group each

typedef __attribute__((ext_vector_type(8))) _Float16 f16x8;
typedef __attribute__((ext_vector_type(2))) _Float16 f16x2;
typedef __attribute__((ext_vector_type(4))) float    f32x4;

// ---------------------------------------------------------------------------
// Pre-pass: x [256][4096] f32 -> xw f16 fragment layout (d_ws, 2 MB):
//   xw[m_blk(4)][t(32)][k8(16)][m(64)] ; 16B unit = 8 f16 of one row's k-octet,
//   word p = (col k8*8+p, k8*8+p+4) pair (cvt_pkrtz lo/hi). No swizzle (no LDS).
// ---------------------------------------------------------------------------
__global__ __launch_bounds__(256, 2)
void xpack(const float* __restrict__ x, uint4* __restrict__ xw)
{
    const int g  = blockIdx.x * 256 + threadIdx.x;   // 131072 threads
    const int m  = g >> 9;
    const int c8 = g & 511;
    const int t  = c8 >> 4;
    const int k8 = c8 & 15;

    const float* src = x + (size_t)m * INF + c8 * 8;
    const f32x4 v0 = *(const f32x4*)src;
    const f32x4 v1 = *(const f32x4*)(src + 4);
    uint32_t d[4];
    #pragma unroll
    for (int p = 0; p < 4; ++p)
        d[p] = __builtin_bit_cast(uint32_t, __builtin_amdgcn_cvt_pkrtz(v0[p], v1[p]));

    const size_t oi = ((size_t)(m >> 6) * 32 + t) * 1024 + k8 * 64 + (m & 63);
    xw[oi] = make_uint4(d[0], d[1], d[2], d[3]);
}

// ---------------------------------------------------------------------------
// Fragment-direct GEMM: NO LDS, NO barriers. 4 independent waves per block.
// Wave = 64 rows x 32 cols. A f16x8 frags read straight from xw (L2);
// B dequantized qweight->f16 in registers (zero+scale folded), MFMA direct.
// ---------------------------------------------------------------------------

// Issue next-tile B raw loads into reg set S (8 qweight words + 2 zeros + 2 scales)
#define ISSUE_B(S, T) do { \
    const int _t = (T); \
    const int* _qw = qwl + (size_t)_t * 16 * OUTF; \
    _Pragma("unroll") for (int kk = 0; kk < 4; ++kk) { \
        w8##S[kk * 2 + 0] = (uint32_t)_qw[(size_t)kk * 4 * OUTF]; \
        w8##S[kk * 2 + 1] = (uint32_t)_qw[(size_t)kk * 4 * OUTF + 16]; } \
    zwa##S = qzeros[_t * QZ_COLS + zc]; \
    zwb##S = qzeros[_t * QZ_COLS + zc + 2]; \
    sfa##S = scales[_t * OUTF + nw0 + l15]; \
    sfb##S = scales[_t * OUTF + nw0 + 16 + l15]; \
} while (0)

#define LOADA(BUF, T, KK) do { \
    const uint4* _ap = abase + (size_t)(T) * 1024 + (KK) * 256 + aoff; \
    _Pragma("unroll") for (int i = 0; i < 4; ++i) \
        areg##BUF[i] = __builtin_bit_cast(f16x8, _ap[i * 16]); \
} while (0)

// One tile: consume B set CUR (tile T), prefetch B set NXT (tile T+1)
#define TILE_BODY(CUR, NXT, T) do { \
    const int _zA = ((zwa##CUR >> zsh) & 15) + 1; \
    const int _zB = ((zwb##CUR >> zsh) & 15) + 1; \
    const _Float16 _hzA = (_Float16)(float)(1024 + _zA); \
    const _Float16 _hzB = (_Float16)(float)(1024 + _zB); \
    const f16x2 z2a = {_hzA, _hzA}, z2b = {_hzB, _hzB}; \
    const _Float16 _hsA = (_Float16)sfa##CUR, _hsB = (_Float16)sfb##CUR; \
    const f16x2 s2a = {_hsA, _hsA}, s2b = {_hsB, _hsB}; \
    LOADA(E, (T), 0); \
    ISSUE_B(NXT, ((T) + 1 < NTILES) ? (T) + 1 : NTILES - 1); \
    _Pragma("unroll") for (int kk = 0; kk < 4; ++kk) { \
        if (kk == 0) LOADA(O, (T), 1); \
        if (kk == 1) LOADA(E, (T), 2); \
        if (kk == 2) LOADA(O, (T), 3); \
        const uint32_t _w0 = w8##CUR[kk * 2 + 0]; \
        const uint32_t _w1 = w8##CUR[kk * 2 + 1]; \
        uint32_t _b0[4], _b1[4]; \
        _Pragma("unroll") for (int p = 0; p < 4; ++p) { \
            const uint32_t _v0 = ((_w0 >> (4 * p)) & 0x000F000Fu) | 0x64006400u; \
            const uint32_t _v1 = ((_w1 >> (4 * p)) & 0x000F000Fu) | 0x64006400u; \
            _b0[p] = __builtin_bit_cast(uint32_t, \
                        (__builtin_bit_cast(f16x2, _v0) - z2a) * s2a); \
            _b1[p] = __builtin_bit_cast(uint32_t, \
                        (__builtin_bit_cast(f16x2, _v1) - z2b) * s2b); } \
        const f16x8 bf0 = __builtin_bit_cast(f16x8, make_uint4(_b0[0], _b0[1], _b0[2], _b0[3])); \
        const f16x8 bf1 = __builtin_bit_cast(f16x8, make_uint4(_b1[0], _b1[1], _b1[2], _b1[3])); \
        _Pragma("unroll") for (int i = 0; i < 4; ++i) { \
            if ((kk & 1) == 0) { \
                acc[i][0] = __builtin_amdgcn_mfma_f32_16x16x32_f16(aregE[i], bf0, acc[i][0], 0, 0, 0); \
                acc[i][1] = __builtin_amdgcn_mfma_f32_16x16x32_f16(aregE[i], bf1, acc[i][1], 0, 0, 0); \
            } else { \
                acc[i][0] = __builtin_amdgcn_mfma_f32_16x16x32_f16(aregO[i], bf0, acc[i][0], 0, 0, 0); \
                acc[i][1] = __builtin_amdgcn_mfma_f32_16x16x32_f16(aregO[i], bf1, acc[i][1], 0, 0, 0); \
            } } \
    } \
} while (0)

__global__ __launch_bounds__(256, 2)
void qlin_mfma(const uint4* __restrict__ xw,
               const float* __restrict__ scales,
               const float* __restrict__ bias,
               const int*   __restrict__ qweight,
               const int*   __restrict__ qzeros,
               float*       __restrict__ out)
{
    const int tid   = threadIdx.x;
    const int m_blk = blockIdx.x;                 // 0..3  (fast dim: L2 reuse of qweight)
    const int nsup  = blockIdx.y;                 // 0..85
    const int wv    = tid >> 6;                   // 4 independent waves
    const int lane  = tid & 63;
    const int l15   = lane & 15;
    const int l4    = lane >> 4;

    const int nw0 = nsup * 128 + wv * 32;         // wave's 32-col slab
    const int m0  = m_blk * 64;

    f32x4 acc[4][2];
    #pragma unroll
    for (int i = 0; i < 4; ++i) {
        acc[i][0] = f32x4{0.f, 0.f, 0.f, 0.f};
        acc[i][1] = f32x4{0.f, 0.f, 0.f, 0.f};
    }

    // per-lane bases
    const int zsh = (l15 & 7) * 4;
    const int zc  = (nw0 + l15) >> 3;
    const int* qwl = qweight + (size_t)l4 * OUTF + nw0 + l15;     // + t*16*OUTF + kk*4*OUTF + j*16
    const uint4* abase = xw + (size_t)m_blk * 32 * 1024;
    const int aoff = l4 * 64 + l15;                                // + t*1024 + kk*256 + i*16

    // B prefetch sets + A double-buffer (all statically indexed)
    uint32_t w8A[8], w8B[8];
    int zwaA, zwbA, zwaB, zwbB;
    float sfaA, sfbA, sfaB, sfbB;
    f16x8 aregE[4], aregO[4];

    ISSUE_B(A, 0);

    for (int t = 0; t < NTILES; t += 2) {
        TILE_BODY(A, B, t);
        TILE_BODY(B, A, t + 1);
    }

    // ---- epilogue: row = i*16 + l4*4 + r, col = j*16 + l15 ----
    #pragma unroll
    for (int j = 0; j < 2; ++j) {
        const int col = nw0 + j * 16 + l15;
        const float bv = bias[col];
        #pragma unroll
        for (int i = 0; i < 4; ++i) {
            const int row0 = m0 + i * 16 + l4 * 4;
            #pragma unroll
            for (int r = 0; r < 4; ++r)
                out[(size_t)(row0 + r) * OUTF + col] = acc[i][j][r] + bv;
        }
    }
}

extern "C" void kernel_launch(void* const* d_in, const int* in_sizes, int n_in,
                              void* d_out, int out_size, void* d_ws, size_t ws_size,
                              hipStream_t stream)
{
    const float* x       = (const float*)d_in[0];
    const float* scales  = (const float*)d_in[1];
    const float* bias    = (const float*)d_in[2];
    const int*   qweight = (const int*)d_in[3];
    const int*   qzeros  = (const int*)d_in[4];
    // d_in[5] = g_idx : deterministic (i // 128), not needed on device
    float* out = (float*)d_out;
    uint4* xw  = (uint4*)d_ws;   // 2 MiB fragment-layout f16 copy of x

    xpack<<<dim3(512), dim3(256), 0, stream>>>(x, xw);
    dim3 grid(4, OUTF / 128);    // (4, 86) = 344 blocks x 4 waves; m_blk fastest
    qlin_mfma<<<grid, dim3(256), 0, stream>>>(xw, scales, bias, qweight, qzeros, out);
}